// Round 4
// baseline (524.943 us; speedup 1.0000x reference)
//
#include <hip/hip_runtime.h>
#include <hip/hip_bf16.h>
#include <math.h>

#define SEQL 2048
#define NB   4
#define HID  4096
#define DM   128
#define DIN  256
#define DST  16
#define HD   64
#define NH   4
#define CONV_DIM 288
#define DPROJ 552
#define MROWS (SEQL*NB)      // 8192
#define TCH 32
#define NCHUNK (SEQL/TCH)    // 64
#define KSPLIT 2

typedef __attribute__((ext_vector_type(8))) short short8;
typedef __attribute__((ext_vector_type(4))) float f32x4;

__device__ __forceinline__ float siluf(float v){ return v / (1.f + expf(-v)); }
__device__ __forceinline__ float geluf(float v){ return 0.5f*v*(1.f + erff(v*0.70710678118654752f)); }
__device__ __forceinline__ float wave_sum(float v){
    #pragma unroll
    for (int o = 32; o > 0; o >>= 1) v += __shfl_xor(v, o, 64);
    return v;
}
__device__ __forceinline__ unsigned bfpack2(float a, float b){
    __hip_bfloat162 v = __float22bfloat162_rn(make_float2(a, b));
    return *reinterpret_cast<unsigned*>(&v);
}

// ---------------- prep: convert weights to bf16 (in_w padded 552->560 rows)
__global__ __launch_bounds__(256) void k_prep_w(const float* __restrict__ w_down,
    const float* __restrict__ w_up, const float* __restrict__ in_w,
    const float* __restrict__ out_w,
    __hip_bfloat16* __restrict__ wd, __hip_bfloat16* __restrict__ wu,
    __hip_bfloat16* __restrict__ wi, __hip_bfloat16* __restrict__ wo)
{
    int idx = blockIdx.x*256 + threadIdx.x;
    if (idx < 524288) { wd[idx] = __float2bfloat16(w_down[idx]); return; }
    idx -= 524288;
    if (idx < 524288) { wu[idx] = __float2bfloat16(w_up[idx]); return; }
    idx -= 524288;
    if (idx < 71680) { wi[idx] = (idx < 552*128) ? __float2bfloat16(in_w[idx]) : __float2bfloat16(0.f); return; }
    idx -= 71680;
    if (idx < 32768) { wo[idx] = __float2bfloat16(out_w[idx]); }
}

// ---------------- K1: down-proj MFMA, split-K x2, partial out
__global__ __launch_bounds__(256) void k_down_mfma(const float* __restrict__ x,
    const __hip_bfloat16* __restrict__ wbf, float* __restrict__ partial)
{
    __shared__ __align__(16) short Abuf[64][72];
    __shared__ __align__(16) short Wbuf[128][72];
    const int tid = threadIdx.x;
    const int m0 = blockIdx.x * 64;
    const int ks = blockIdx.y;
    const int b  = m0 >> 11, l0 = m0 & 2047;
    const int lane = tid & 63, wv = tid >> 6;
    const int fr = lane & 15, q = lane >> 4;
    f32x4 acc[8];
    #pragma unroll
    for (int i = 0; i < 8; ++i) acc[i] = (f32x4){0.f,0.f,0.f,0.f};

    const int arow = tid >> 2, aseg = tid & 3;   // A: 4 thr/row, 16 floats
    const int wrow = tid >> 1, wseg = tid & 1;   // W: 2 thr/row, 32 shorts

    const int kbase = ks * (HID/KSPLIT);
    for (int k0 = kbase; k0 < kbase + HID/KSPLIT; k0 += 64) {
        const float4* ap = (const float4*)(x + (size_t)((l0 + arow)*NB + b)*HID + k0 + aseg*16);
        float4 f0 = ap[0], f1 = ap[1], f2 = ap[2], f3 = ap[3];
        const uint4* wp = (const uint4*)(wbf + (size_t)wrow*HID + k0 + wseg*32);
        uint4 w0 = wp[0], w1 = wp[1], w2 = wp[2], w3 = wp[3];
        uint4 pk0, pk1;
        pk0.x = bfpack2(f0.x,f0.y); pk0.y = bfpack2(f0.z,f0.w);
        pk0.z = bfpack2(f1.x,f1.y); pk0.w = bfpack2(f1.z,f1.w);
        pk1.x = bfpack2(f2.x,f2.y); pk1.y = bfpack2(f2.z,f2.w);
        pk1.z = bfpack2(f3.x,f3.y); pk1.w = bfpack2(f3.z,f3.w);
        uint4* adst = (uint4*)&Abuf[arow][aseg*16];
        adst[0] = pk0; adst[1] = pk1;
        uint4* wdst = (uint4*)&Wbuf[wrow][wseg*32];
        wdst[0] = w0; wdst[1] = w1; wdst[2] = w2; wdst[3] = w3;
        __syncthreads();
        #pragma unroll
        for (int kh = 0; kh < 2; ++kh) {
            short8 af = *reinterpret_cast<const short8*>(&Abuf[wv*16 + fr][kh*32 + q*8]);
            #pragma unroll
            for (int ns = 0; ns < 8; ++ns) {
                short8 bf = *reinterpret_cast<const short8*>(&Wbuf[ns*16 + fr][kh*32 + q*8]);
                acc[ns] = __builtin_amdgcn_mfma_f32_16x16x32_bf16(af, bf, acc[ns], 0, 0, 0);
            }
        }
        __syncthreads();
    }
    #pragma unroll
    for (int ns = 0; ns < 8; ++ns)
        #pragma unroll
        for (int r = 0; r < 4; ++r)
            partial[((size_t)ks*MROWS + m0 + wv*16 + q*4 + r)*DM + ns*16 + fr] = acc[ns][r];
}

// ---------------- K1b: partial reduce + bias + GELU -> xmid fp32 + u_bf
__global__ __launch_bounds__(256) void k_down_fix(const float* __restrict__ partial,
    const float* __restrict__ bias, float* __restrict__ xmid,
    __hip_bfloat16* __restrict__ ubf)
{
    size_t i4 = ((size_t)blockIdx.x*256 + threadIdx.x)*4;
    int n = (int)(i4 & (DM-1));
    float4 p0 = *(const float4*)&partial[i4];
    float4 p1 = *(const float4*)&partial[(size_t)MROWS*DM + i4];
    float4 bv = *(const float4*)&bias[n];
    float4 v;
    v.x = geluf(p0.x + p1.x + bv.x);
    v.y = geluf(p0.y + p1.y + bv.y);
    v.z = geluf(p0.z + p1.z + bv.z);
    v.w = geluf(p0.w + p1.w + bv.w);
    *(float4*)&xmid[i4] = v;
    uint2 pk; pk.x = bfpack2(v.x, v.y); pk.y = bfpack2(v.z, v.w);
    *(uint2*)&ubf[i4] = pk;
}

// ---------------- in-proj MFMA: zx = u(bf16) @ in_w(bf16)^T  (N padded to 560)
__global__ __launch_bounds__(256) void k_proj_in(const __hip_bfloat16* __restrict__ ubf,
    const __hip_bfloat16* __restrict__ wbf, float* __restrict__ zx)
{
    __shared__ __align__(16) short Abuf[64][136];
    __shared__ __align__(16) short Wbuf[80][136];
    const int tid = threadIdx.x;
    const int m0 = blockIdx.x*64;
    const int n0 = blockIdx.y*80;
    for (int i = tid; i < 64*16; i += 256) {
        int r = i >> 4, s = i & 15;
        *(uint4*)&Abuf[r][s*8] = *(const uint4*)&ubf[(size_t)(m0+r)*DM + s*8];
    }
    for (int i = tid; i < 80*16; i += 256) {
        int r = i >> 4, s = i & 15;
        *(uint4*)&Wbuf[r][s*8] = *(const uint4*)&wbf[(size_t)(n0+r)*DM + s*8];
    }
    __syncthreads();
    const int lane = tid & 63, wv = tid >> 6, fr = lane & 15, q = lane >> 4;
    f32x4 acc[5];
    #pragma unroll
    for (int i = 0; i < 5; ++i) acc[i] = (f32x4){0.f,0.f,0.f,0.f};
    #pragma unroll
    for (int kt = 0; kt < 4; ++kt) {
        short8 af = *reinterpret_cast<const short8*>(&Abuf[wv*16 + fr][kt*32 + q*8]);
        #pragma unroll
        for (int ns = 0; ns < 5; ++ns) {
            short8 bf = *reinterpret_cast<const short8*>(&Wbuf[ns*16 + fr][kt*32 + q*8]);
            acc[ns] = __builtin_amdgcn_mfma_f32_16x16x32_bf16(af, bf, acc[ns], 0, 0, 0);
        }
    }
    #pragma unroll
    for (int ns = 0; ns < 5; ++ns) {
        int n = n0 + ns*16 + fr;
        if (n < DPROJ) {
            #pragma unroll
            for (int r = 0; r < 4; ++r)
                zx[(size_t)(m0 + wv*16 + q*4 + r)*DPROJ + n] = acc[ns][r];
        }
    }
}

// ---------------- fused conv + dt/dA + chunk-local scan states.
// Block = (chunk c, batch b); 512 threads = 8 waves; wave g = (dir,h) group.
// fw group uses chunk c; bw group emits chunk (NCHUNK-1-c): same 32 rows reversed.
__global__ __launch_bounds__(512) void k_convscan(const float* __restrict__ zx,
    const float* __restrict__ cw, const float* __restrict__ cb,
    const float* __restrict__ dt_bias, const float* __restrict__ A_log,
    float* __restrict__ xBC, float* __restrict__ dtbuf, float* __restrict__ dAbuf,
    float* __restrict__ Sbuf, float* __restrict__ Pbuf)
{
    const int bid = blockIdx.x;
    const int c = bid & (NCHUNK-1);
    const int b = bid >> 6;
    const int tid = threadIdx.x;
    __shared__ __align__(16) float xs_s[TCH][CONV_DIM];   // 36.9 KB
    __shared__ float dt_s[8][TCH], dA_s[8][TCH];          // 2 KB

    // conv7 + silu: 32 rows x 288 ch, write LDS + global
    {
        const int rr0 = tid >> 5;       // 0..15
        const int cc0 = tid & 31;
        #pragma unroll
        for (int band = 0; band < 2; ++band) {
            int rr = band*16 + rr0;
            int l = c*TCH + rr;
            #pragma unroll
            for (int j = 0; j < 9; ++j) {
                int cc = j*32 + cc0;
                float acc = cb[cc];
                #pragma unroll
                for (int k = 0; k < 7; ++k) {
                    int l2 = l - 6 + k;
                    if (l2 >= 0)
                        acc = fmaf(zx[(size_t)(b*SEQL + l2)*DPROJ + DIN + cc], cw[cc*7 + k], acc);
                }
                float v = siluf(acc);
                xs_s[rr][cc] = v;
                xBC[(size_t)(b*SEQL + l)*CONV_DIM + cc] = v;
            }
        }
    }
    // dt/dA for all 8 groups (threads 0..255), store transposed for scan_out
    if (tid < 256) {
        int g = tid >> 5, kk = tid & 31;
        int dirg = g >> 2, hg = g & 3;
        int l = dirg ? (c*TCH + TCH-1 - kk) : (c*TCH + kk);
        float dtraw = zx[(size_t)(b*SEQL + l)*DPROJ + 544 + dirg*NH + hg] + dt_bias[hg];
        float dt = dtraw > 20.f ? dtraw : log1pf(expf(dtraw));
        float dA = expf(dt * (-expf(A_log[hg])));
        dt_s[g][kk] = dt; dA_s[g][kk] = dA;
        int cs = dirg ? (NCHUNK-1 - c) : c;
        size_t o = (size_t)(g*NB + b)*SEQL + cs*TCH + kk;
        dtbuf[o] = dt; dAbuf[o] = dA;
    }
    __syncthreads();
    // scan: wave g handles its (dir,h); lane: pg=lane>>2 -> 4 p-rows, ng=lane&3 -> n-quad
    {
        const int g = tid >> 6;
        const int lane = tid & 63;
        const int dirg = g >> 2, hg = g & 3;
        const int pg = lane >> 2, ng = lane & 3;
        float s[4][4];
        #pragma unroll
        for (int i = 0; i < 4; ++i)
            #pragma unroll
            for (int j = 0; j < 4; ++j) s[i][j] = 0.f;
        for (int k2 = 0; k2 < TCH; ++k2) {
            int rr = dirg ? (TCH-1 - k2) : k2;
            float dAv = dA_s[g][k2];
            float dtv = dt_s[g][k2];
            float4 bv = *(const float4*)&xs_s[rr][DIN + ng*4];
            float xa[4];
            #pragma unroll
            for (int i = 0; i < 4; ++i) xa[i] = dtv * xs_s[rr][hg*HD + pg*4 + i];
            #pragma unroll
            for (int i = 0; i < 4; ++i) {
                s[i][0] = fmaf(dAv, s[i][0], xa[i]*bv.x);
                s[i][1] = fmaf(dAv, s[i][1], xa[i]*bv.y);
                s[i][2] = fmaf(dAv, s[i][2], xa[i]*bv.z);
                s[i][3] = fmaf(dAv, s[i][3], xa[i]*bv.w);
            }
        }
        int cs = dirg ? (NCHUNK-1 - c) : c;
        size_t sb = ((size_t)(g*NB + b)*NCHUNK + cs) * 1024;
        #pragma unroll
        for (int i = 0; i < 4; ++i) {
            float4 v = {s[i][0], s[i][1], s[i][2], s[i][3]};
            *(float4*)&Sbuf[sb + (size_t)((pg*4+i)*16 + ng*4)] = v;
        }
        float pv = (lane < TCH) ? dA_s[g][lane] : 1.f;
        #pragma unroll
        for (int o = 32; o > 0; o >>= 1) pv *= __shfl_xor(pv, o, 64);
        if (lane == 0) Pbuf[(size_t)(g*NB + b)*NCHUNK + cs] = pv;
    }
}

// ---------------- replay with in-block prefix combine (no Hbuf kernel), emit y
__global__ __launch_bounds__(256) void k_scan_out2(const float* __restrict__ xBC,
    const float* __restrict__ dtbuf, const float* __restrict__ dAbuf,
    const float* __restrict__ Sbuf, const float* __restrict__ Pbuf,
    float* __restrict__ yfw, float* __restrict__ ybw)
{
    const int bid = blockIdx.x;
    const int cs = bid & (NCHUNK-1);
    const int chain = bid >> 6;            // (dir*4+h)*4+b
    const int b = chain & 3;
    const int h = (chain >> 2) & 3;
    const int dir = chain >> 4;
    const int tid = threadIdx.x;
    __shared__ float dA_s[TCH], dt_s[TCH];
    __shared__ __align__(16) float Xs[TCH][HD];
    __shared__ __align__(16) float Bs[TCH][DST];
    __shared__ __align__(16) float Cs[TCH][DST];
    const size_t tb = (size_t)chain*SEQL + cs*TCH;
    if (tid < TCH) { dt_s[tid] = dtbuf[tb + tid]; dA_s[tid] = dAbuf[tb + tid]; }
    #pragma unroll
    for (int t = 0; t < 2; ++t) {
        int idx = t*256 + tid;
        int k2 = idx >> 4, p4 = (idx & 15)*4;
        int l2 = dir ? (SEQL-1 - (cs*TCH + k2)) : (cs*TCH + k2);
        *(float4*)&Xs[k2][p4] = *(const float4*)&xBC[(size_t)(b*SEQL + l2)*CONV_DIM + h*HD + p4];
    }
    if (tid < 128) {
        int k2 = tid >> 2, n4 = (tid & 3)*4;
        int l2 = dir ? (SEQL-1 - (cs*TCH + k2)) : (cs*TCH + k2);
        *(float4*)&Bs[k2][n4] = *(const float4*)&xBC[(size_t)(b*SEQL + l2)*CONV_DIM + DIN + n4];
        *(float4*)&Cs[k2][n4] = *(const float4*)&xBC[(size_t)(b*SEQL + l2)*CONV_DIM + DIN + DST + n4];
    }
    // H-init: prefix over earlier chunks of this chain (batched, predicated)
    const int lane = tid & 63, w = tid >> 6;
    const int p = w*16 + (lane >> 2), ng = lane & 3;
    const float* Sg = Sbuf + (size_t)chain*NCHUNK*1024 + (p*16 + ng*4);
    const float* Pg = Pbuf + (size_t)chain*NCHUNK;
    float4 carry = {0.f,0.f,0.f,0.f};
    for (int jb = 0; jb < NCHUNK; jb += 8) {
        if (jb >= cs) break;
        float4 sv[8]; float pw[8];
        #pragma unroll
        for (int k = 0; k < 8; ++k) {
            int j = jb + k;
            if (j < cs) { sv[k] = *(const float4*)(Sg + (size_t)j*1024); pw[k] = Pg[j]; }
            else        { sv[k] = (float4){0.f,0.f,0.f,0.f}; pw[k] = 1.f; }
        }
        #pragma unroll
        for (int k = 0; k < 8; ++k) {
            carry.x = fmaf(pw[k], carry.x, sv[k].x);
            carry.y = fmaf(pw[k], carry.y, sv[k].y);
            carry.z = fmaf(pw[k], carry.z, sv[k].z);
            carry.w = fmaf(pw[k], carry.w, sv[k].w);
        }
    }
    __syncthreads();
    float s0 = carry.x, s1 = carry.y, s2 = carry.z, s3 = carry.w;
    float* yout = dir ? ybw : yfw;
    for (int k2 = 0; k2 < TCH; ++k2) {
        float dAv = dA_s[k2];
        float xa  = dt_s[k2] * Xs[k2][p];
        float4 bv = *(const float4*)&Bs[k2][ng*4];
        float4 cv = *(const float4*)&Cs[k2][ng*4];
        s0 = fmaf(dAv, s0, xa*bv.x);
        s1 = fmaf(dAv, s1, xa*bv.y);
        s2 = fmaf(dAv, s2, xa*bv.z);
        s3 = fmaf(dAv, s3, xa*bv.w);
        float yp = s0*cv.x + s1*cv.y + s2*cv.z + s3*cv.w;
        yp += __shfl_xor(yp, 1, 64);
        yp += __shfl_xor(yp, 2, 64);
        if (ng == 0) {
            int l2 = dir ? (SEQL-1 - (cs*TCH + k2)) : (cs*TCH + k2);
            yout[(size_t)(b*SEQL + l2)*DIN + h*HD + p] = yp;
        }
    }
}

// ---------------- fused epi (shift+D-skip+gate+RMSNorm) + out-proj MFMA.
// Phase 1: wave w owns rows r=4t+w; 64 lanes x 4 dims cover the full 256-dim row
// (wave-level reductions only). yn goes straight into LDS Ys. Phase 2: MFMA.
template<int PASS>
__global__ __launch_bounds__(256) void k_epiproj(const float* __restrict__ zx,
    const float* __restrict__ xBC, const float* __restrict__ yfw,
    const float* __restrict__ ybw, const float* __restrict__ fcD_w,
    const float* __restrict__ Dv, const float* __restrict__ norm_w,
    const __hip_bfloat16* __restrict__ wbf, const float* __restrict__ xmid,
    const float* __restrict__ gate1,
    __hip_bfloat16* __restrict__ ubf, __hip_bfloat16* __restrict__ hcbf)
{
    __shared__ __align__(16) short Ys[64][264];   // 33.8 KB, full K=256 (+pad)
    __shared__ __align__(16) short Wq[64][136];   // 17.4 KB quarter tile
    const int tid = threadIdx.x;
    const int m0 = blockIdx.x*64;
    const int lane = tid & 63, w = tid >> 6;
    const int d0 = lane*4;
    float4 fc0 = *(const float4*)&fcD_w[0*DIN + d0];
    float4 fc1 = *(const float4*)&fcD_w[1*DIN + d0];
    float4 fc2 = *(const float4*)&fcD_w[2*DIN + d0];
    float4 fc3 = *(const float4*)&fcD_w[3*DIN + d0];
    float4 nw  = *(const float4*)&norm_w[d0];
    float dvh  = Dv[lane >> 4];
    for (int t = 0; t < 16; ++t) {
        int r = t*4 + w;
        int m = m0 + r;
        int l = m & (SEQL-1);
        float4 xs = *(const float4*)&xBC[(size_t)m*CONV_DIM + d0];
        float4 yv = {0.f,0.f,0.f,0.f};
        if (l > 0) {
            float4 yf = *(const float4*)&yfw[(size_t)(m-1)*DIN + d0];
            yv.x += yf.x; yv.y += yf.y; yv.z += yf.z; yv.w += yf.w;
        }
        if (l < SEQL-1) {
            float4 yb = *(const float4*)&ybw[(size_t)(m+1)*DIN + d0];
            yv.x += yb.x; yv.y += yb.y; yv.z += yb.z; yv.w += yb.w;
        }
        float p0 = xs.x*fc0.x + xs.y*fc0.y + xs.z*fc0.z + xs.w*fc0.w;
        float p1 = xs.x*fc1.x + xs.y*fc1.y + xs.z*fc1.z + xs.w*fc1.w;
        float p2 = xs.x*fc2.x + xs.y*fc2.y + xs.z*fc2.z + xs.w*fc2.w;
        float p3 = xs.x*fc3.x + xs.y*fc3.y + xs.z*fc3.z + xs.w*fc3.w;
        p0 = wave_sum(p0); p1 = wave_sum(p1); p2 = wave_sum(p2); p3 = wave_sum(p3);
        int hh = lane >> 4;
        float scal = (hh == 0 ? p0 : hh == 1 ? p1 : hh == 2 ? p2 : p3) + dvh;
        yv.x = fmaf(xs.x, scal, yv.x);
        yv.y = fmaf(xs.y, scal, yv.y);
        yv.z = fmaf(xs.z, scal, yv.z);
        yv.w = fmaf(xs.w, scal, yv.w);
        float4 z4 = *(const float4*)&zx[(size_t)m*DPROJ + d0];
        float4 yz;
        yz.x = yv.x * siluf(z4.x);
        yz.y = yv.y * siluf(z4.y);
        yz.z = yv.z * siluf(z4.z);
        yz.w = yv.w * siluf(z4.w);
        float qq = wave_sum(yz.x*yz.x + yz.y*yz.y + yz.z*yz.z + yz.w*yz.w);
        float rinv = rsqrtf(qq*(1.f/DIN) + 1e-5f);
        uint2 pk;
        pk.x = bfpack2(yz.x*rinv*nw.x, yz.y*rinv*nw.y);
        pk.y = bfpack2(yz.z*rinv*nw.z, yz.w*rinv*nw.w);
        *(uint2*)&Ys[r][d0] = pk;
    }
    // phase 2: h = yn @ out_w^T  (W in 64x128 quarters)
    const int fr = lane & 15, q = lane >> 4;
    f32x4 acc[8];
    #pragma unroll
    for (int i = 0; i < 8; ++i) acc[i] = (f32x4){0.f,0.f,0.f,0.f};
    #pragma unroll
    for (int it = 0; it < 4; ++it) {
        const int nh = it >> 1, kb = it & 1;
        __syncthreads();
        #pragma unroll
        for (int i2 = 0; i2 < 4; ++i2) {
            int i = i2*256 + tid;
            int rw = i >> 4, sS = i & 15;
            *(uint4*)&Wq[rw][sS*8] = *(const uint4*)&wbf[(size_t)(nh*64 + rw)*DIN + kb*128 + sS*8];
        }
        __syncthreads();
        #pragma unroll
        for (int kt = 0; kt < 4; ++kt) {
            short8 af = *reinterpret_cast<const short8*>(&Ys[w*16 + fr][kb*128 + kt*32 + q*8]);
            #pragma unroll
            for (int nsq = 0; nsq < 4; ++nsq) {
                short8 bf = *reinterpret_cast<const short8*>(&Wq[nsq*16 + fr][kt*32 + q*8]);
                acc[nh*4 + nsq] = __builtin_amdgcn_mfma_f32_16x16x32_bf16(af, bf, acc[nh*4 + nsq], 0, 0, 0);
            }
        }
    }
    float ca = 0.f, cbl = 0.f;
    if (PASS == 1) {
        float al = 1.f / (1.f + expf(-gate1[0]));
        ca = 1.f + al; cbl = 1.f - al;
    }
    #pragma unroll
    for (int ns = 0; ns < 8; ++ns)
        #pragma unroll
        for (int r4 = 0; r4 < 4; ++r4) {
            int m = m0 + w*16 + q*4 + r4, n = ns*16 + fr;
            float v = acc[ns][r4];
            if (PASS == 0) {
                ubf[(size_t)m*DM + n] = __float2bfloat16(v);
            } else {
                float xm = xmid[(size_t)m*DM + n];
                hcbf[(size_t)m*DM + n] = __float2bfloat16(ca*xm + cbl*v);
            }
        }
}

// ---------------- up-proj MFMA + bias + residual + transpose store
__global__ __launch_bounds__(256) void k_up_mfma(const __hip_bfloat16* __restrict__ hc,
    const __hip_bfloat16* __restrict__ wbf, const float* __restrict__ b_up,
    const float* __restrict__ x, float* __restrict__ out)
{
    __shared__ __align__(16) short Abuf[64][136];
    __shared__ __align__(16) short Wbuf[128][136];
    const int tid = threadIdx.x;
    const int m0 = blockIdx.x*64;
    const int n0 = blockIdx.y*128;
    for (int i = tid; i < 64*16; i += 256) {
        int r = i >> 4, s = i & 15;
        *(uint4*)&Abuf[r][s*8] = *(const uint4*)&hc[(size_t)(m0+r)*DM + s*8];
    }
    for (int i = tid; i < 128*16; i += 256) {
        int r = i >> 4, s = i & 15;
        *(uint4*)&Wbuf[r][s*8] = *(const uint4*)&wbf[(size_t)(n0+r)*DM + s*8];
    }
    __syncthreads();
    const int lane = tid & 63, wv = tid >> 6, fr = lane & 15, q = lane >> 4;
    f32x4 acc[8];
    #pragma unroll
    for (int i = 0; i < 8; ++i) acc[i] = (f32x4){0.f,0.f,0.f,0.f};
    #pragma unroll
    for (int kt = 0; kt < 4; ++kt) {
        short8 af = *reinterpret_cast<const short8*>(&Abuf[wv*16 + fr][kt*32 + q*8]);
        #pragma unroll
        for (int ns = 0; ns < 8; ++ns) {
            short8 bf = *reinterpret_cast<const short8*>(&Wbuf[ns*16 + fr][kt*32 + q*8]);
            acc[ns] = __builtin_amdgcn_mfma_f32_16x16x32_bf16(af, bf, acc[ns], 0, 0, 0);
        }
    }
    #pragma unroll
    for (int r = 0; r < 4; ++r) {
        int m = m0 + wv*16 + q*4 + r;
        int b = m >> 11, l = m & 2047;
        size_t rowbase = (size_t)(l*NB + b)*HID + n0;
        #pragma unroll
        for (int ns = 0; ns < 8; ++ns) {
            int n = ns*16 + fr;
            out[rowbase + n] = acc[ns][r] + b_up[n0 + n] + x[rowbase + n];
        }
    }
}

extern "C" void kernel_launch(void* const* d_in, const int* in_sizes, int n_in,
                              void* d_out, int out_size, void* d_ws, size_t ws_size,
                              hipStream_t stream)
{
    const float* x       = (const float*)d_in[0];
    const float* w_down  = (const float*)d_in[1];
    const float* b_down  = (const float*)d_in[2];
    const float* w_up    = (const float*)d_in[3];
    const float* b_up    = (const float*)d_in[4];
    const float* gate1   = (const float*)d_in[5];
    const float* in_w    = (const float*)d_in[6];
    const float* conv_w  = (const float*)d_in[7];
    const float* conv_b  = (const float*)d_in[8];
    const float* dt_bias = (const float*)d_in[9];
    const float* A_log   = (const float*)d_in[10];
    const float* Dv      = (const float*)d_in[11];
    const float* fcD_w   = (const float*)d_in[12];
    const float* norm_w  = (const float*)d_in[13];
    const float* out_w   = (const float*)d_in[14];
    float* out = (float*)d_out;
    float* ws  = (float*)d_ws;

    size_t off = 0;
    float* xmid = ws + off; off += (size_t)MROWS*DM;
    float* zx   = ws + off; off += (size_t)MROWS*DPROJ;
    float* xBC  = ws + off; off += (size_t)MROWS*CONV_DIM;
    float* yfw  = ws + off; off += (size_t)MROWS*DIN;
    float* ybw  = ws + off; off += (size_t)MROWS*DIN;
    float* Sbuf = ws + off; off += (size_t)32*NCHUNK*1024;   // 2M floats
    float* Pbuf = ws + off; off += (size_t)32*NCHUNK;
    float* dtbuf= ws + off; off += (size_t)2*NH*NB*SEQL;
    float* dAbuf= ws + off; off += (size_t)2*NH*NB*SEQL;
    __hip_bfloat16* bfb = (__hip_bfloat16*)(ws + off);
    size_t bo = 0;
    __hip_bfloat16* wd_bf = bfb + bo; bo += 524288;
    __hip_bfloat16* wu_bf = bfb + bo; bo += 524288;
    __hip_bfloat16* wi_bf = bfb + bo; bo += 71680;
    __hip_bfloat16* wo_bf = bfb + bo; bo += 32768;
    __hip_bfloat16* u_bf  = bfb + bo; bo += (size_t)MROWS*DM;
    __hip_bfloat16* hc_bf = bfb + bo; bo += (size_t)MROWS*DM;
    float* partial = zx;   // alias: 2*MROWS*DM = 2.1M floats <= MROWS*552 = 4.52M

    k_prep_w<<<4504, 256, 0, stream>>>(w_down, w_up, in_w, out_w, wd_bf, wu_bf, wi_bf, wo_bf);

    dim3 gdown(MROWS/64, KSPLIT);
    k_down_mfma<<<gdown, 256, 0, stream>>>(x, wd_bf, partial);
    k_down_fix<<<MROWS*DM/1024, 256, 0, stream>>>(partial, b_down, xmid, u_bf);

    for (int pass = 0; pass < 2; ++pass) {
        dim3 gin(MROWS/64, 7);
        k_proj_in<<<gin, 256, 0, stream>>>(u_bf, wi_bf, zx);
        k_convscan<<<NCHUNK*NB, 512, 0, stream>>>(zx, conv_w, conv_b, dt_bias, A_log,
                                                  xBC, dtbuf, dAbuf, Sbuf, Pbuf);
        k_scan_out2<<<32*NCHUNK, 256, 0, stream>>>(xBC, dtbuf, dAbuf, Sbuf, Pbuf, yfw, ybw);
        if (pass == 0)
            k_epiproj<0><<<MROWS/64, 256, 0, stream>>>(zx, xBC, yfw, ybw, fcD_w, Dv, norm_w,
                                                       wo_bf, xmid, gate1, u_bf, hc_bf);
        else
            k_epiproj<1><<<MROWS/64, 256, 0, stream>>>(zx, xBC, yfw, ybw, fcD_w, Dv, norm_w,
                                                       wo_bf, xmid, gate1, u_bf, hc_bf);
    }

    dim3 gup(MROWS/64, HID/128);
    k_up_mfma<<<gup, 256, 0, stream>>>(hc_bf, wu_bf, b_up, x, out);
}

// Round 7
// 501.253 us; speedup vs baseline: 1.0473x; 1.0473x over previous
//
#include <hip/hip_runtime.h>
#include <hip/hip_bf16.h>
#include <math.h>

#define SEQL 2048
#define NB   4
#define HID  4096
#define DM   128
#define DIN  256
#define DST  16
#define HD   64
#define NH   4
#define CONV_DIM 288
#define DPROJ 552
#define MROWS (SEQL*NB)      // 8192
#define TCH 64
#define NCHUNK (SEQL/TCH)    // 32
#define KSPLIT 4

typedef __attribute__((ext_vector_type(8))) short short8;
typedef __attribute__((ext_vector_type(4))) float f32x4;

__device__ __forceinline__ float siluf(float v){ return v / (1.f + expf(-v)); }
__device__ __forceinline__ float geluf(float v){ return 0.5f*v*(1.f + erff(v*0.70710678118654752f)); }
__device__ __forceinline__ float wave_sum(float v){
    #pragma unroll
    for (int o = 32; o > 0; o >>= 1) v += __shfl_xor(v, o, 64);
    return v;
}
__device__ __forceinline__ unsigned bfpack2(float a, float b){
    __hip_bfloat162 v = __float22bfloat162_rn(make_float2(a, b));
    return *reinterpret_cast<unsigned*>(&v);
}

// ---------------- prep: convert weights to bf16 (in_w padded 552->560 rows)
__global__ __launch_bounds__(256) void k_prep_w(const float* __restrict__ w_down,
    const float* __restrict__ w_up, const float* __restrict__ in_w,
    const float* __restrict__ out_w,
    __hip_bfloat16* __restrict__ wd, __hip_bfloat16* __restrict__ wu,
    __hip_bfloat16* __restrict__ wi, __hip_bfloat16* __restrict__ wo)
{
    int idx = blockIdx.x*256 + threadIdx.x;
    if (idx < 524288) { wd[idx] = __float2bfloat16(w_down[idx]); return; }
    idx -= 524288;
    if (idx < 524288) { wu[idx] = __float2bfloat16(w_up[idx]); return; }
    idx -= 524288;
    if (idx < 71680) { wi[idx] = (idx < 552*128) ? __float2bfloat16(in_w[idx]) : __float2bfloat16(0.f); return; }
    idx -= 71680;
    if (idx < 32768) { wo[idx] = __float2bfloat16(out_w[idx]); }
}

// ---------------- K1: down-proj MFMA, split-K x4, partial out
__global__ __launch_bounds__(256) void k_down_mfma(const float* __restrict__ x,
    const __hip_bfloat16* __restrict__ wbf, float* __restrict__ partial)
{
    __shared__ __align__(16) short Abuf[64][72];
    __shared__ __align__(16) short Wbuf[128][72];
    const int tid = threadIdx.x;
    const int m0 = blockIdx.x * 64;
    const int ks = blockIdx.y;
    const int b  = m0 >> 11, l0 = m0 & 2047;
    const int lane = tid & 63, wv = tid >> 6;
    const int fr = lane & 15, q = lane >> 4;
    f32x4 acc[8];
    #pragma unroll
    for (int i = 0; i < 8; ++i) acc[i] = (f32x4){0.f,0.f,0.f,0.f};

    const int arow = tid >> 2, aseg = tid & 3;   // A: 4 thr/row, 16 floats
    const int wrow = tid >> 1, wseg = tid & 1;   // W: 2 thr/row, 32 shorts

    const int kbase = ks * (HID/KSPLIT);
    for (int k0 = kbase; k0 < kbase + HID/KSPLIT; k0 += 64) {
        const float4* ap = (const float4*)(x + (size_t)((l0 + arow)*NB + b)*HID + k0 + aseg*16);
        float4 f0 = ap[0], f1 = ap[1], f2 = ap[2], f3 = ap[3];
        const uint4* wp = (const uint4*)(wbf + (size_t)wrow*HID + k0 + wseg*32);
        uint4 w0 = wp[0], w1 = wp[1], w2 = wp[2], w3 = wp[3];
        uint4 pk0, pk1;
        pk0.x = bfpack2(f0.x,f0.y); pk0.y = bfpack2(f0.z,f0.w);
        pk0.z = bfpack2(f1.x,f1.y); pk0.w = bfpack2(f1.z,f1.w);
        pk1.x = bfpack2(f2.x,f2.y); pk1.y = bfpack2(f2.z,f2.w);
        pk1.z = bfpack2(f3.x,f3.y); pk1.w = bfpack2(f3.z,f3.w);
        uint4* adst = (uint4*)&Abuf[arow][aseg*16];
        adst[0] = pk0; adst[1] = pk1;
        uint4* wdst = (uint4*)&Wbuf[wrow][wseg*32];
        wdst[0] = w0; wdst[1] = w1; wdst[2] = w2; wdst[3] = w3;
        __syncthreads();
        #pragma unroll
        for (int kh = 0; kh < 2; ++kh) {
            short8 af = *reinterpret_cast<const short8*>(&Abuf[wv*16 + fr][kh*32 + q*8]);
            #pragma unroll
            for (int ns = 0; ns < 8; ++ns) {
                short8 bf = *reinterpret_cast<const short8*>(&Wbuf[ns*16 + fr][kh*32 + q*8]);
                acc[ns] = __builtin_amdgcn_mfma_f32_16x16x32_bf16(af, bf, acc[ns], 0, 0, 0);
            }
        }
        __syncthreads();
    }
    #pragma unroll
    for (int ns = 0; ns < 8; ++ns)
        #pragma unroll
        for (int r = 0; r < 4; ++r)
            partial[((size_t)ks*MROWS + m0 + wv*16 + q*4 + r)*DM + ns*16 + fr] = acc[ns][r];
}

// ---------------- K1b: partial reduce + bias + GELU -> xmid fp32 + u_bf
__global__ __launch_bounds__(256) void k_down_fix(const float* __restrict__ partial,
    const float* __restrict__ bias, float* __restrict__ xmid,
    __hip_bfloat16* __restrict__ ubf)
{
    size_t i4 = ((size_t)blockIdx.x*256 + threadIdx.x)*4;
    int n = (int)(i4 & (DM-1));
    float4 p0 = *(const float4*)&partial[i4];
    float4 p1 = *(const float4*)&partial[(size_t)MROWS*DM + i4];
    float4 p2 = *(const float4*)&partial[(size_t)2*MROWS*DM + i4];
    float4 p3 = *(const float4*)&partial[(size_t)3*MROWS*DM + i4];
    float4 bv = *(const float4*)&bias[n];
    float4 v;
    v.x = geluf(p0.x + p1.x + p2.x + p3.x + bv.x);
    v.y = geluf(p0.y + p1.y + p2.y + p3.y + bv.y);
    v.z = geluf(p0.z + p1.z + p2.z + p3.z + bv.z);
    v.w = geluf(p0.w + p1.w + p2.w + p3.w + bv.w);
    *(float4*)&xmid[i4] = v;
    uint2 pk; pk.x = bfpack2(v.x, v.y); pk.y = bfpack2(v.z, v.w);
    *(uint2*)&ubf[i4] = pk;
}

// ---------------- in-proj MFMA: zx = u(bf16) @ in_w(bf16)^T  (N padded to 560)
__global__ __launch_bounds__(256) void k_proj_in(const __hip_bfloat16* __restrict__ ubf,
    const __hip_bfloat16* __restrict__ wbf, float* __restrict__ zx)
{
    __shared__ __align__(16) short Abuf[64][136];
    __shared__ __align__(16) short Wbuf[80][136];
    const int tid = threadIdx.x;
    const int m0 = blockIdx.x*64;
    const int n0 = blockIdx.y*80;
    for (int i = tid; i < 64*16; i += 256) {
        int r = i >> 4, s = i & 15;
        *(uint4*)&Abuf[r][s*8] = *(const uint4*)&ubf[(size_t)(m0+r)*DM + s*8];
    }
    for (int i = tid; i < 80*16; i += 256) {
        int r = i >> 4, s = i & 15;
        *(uint4*)&Wbuf[r][s*8] = *(const uint4*)&wbf[(size_t)(n0+r)*DM + s*8];
    }
    __syncthreads();
    const int lane = tid & 63, wv = tid >> 6, fr = lane & 15, q = lane >> 4;
    f32x4 acc[5];
    #pragma unroll
    for (int i = 0; i < 5; ++i) acc[i] = (f32x4){0.f,0.f,0.f,0.f};
    #pragma unroll
    for (int kt = 0; kt < 4; ++kt) {
        short8 af = *reinterpret_cast<const short8*>(&Abuf[wv*16 + fr][kt*32 + q*8]);
        #pragma unroll
        for (int ns = 0; ns < 5; ++ns) {
            short8 bf = *reinterpret_cast<const short8*>(&Wbuf[ns*16 + fr][kt*32 + q*8]);
            acc[ns] = __builtin_amdgcn_mfma_f32_16x16x32_bf16(af, bf, acc[ns], 0, 0, 0);
        }
    }
    #pragma unroll
    for (int ns = 0; ns < 5; ++ns) {
        int n = n0 + ns*16 + fr;
        if (n < DPROJ) {
            #pragma unroll
            for (int r = 0; r < 4; ++r)
                zx[(size_t)(m0 + wv*16 + q*4 + r)*DPROJ + n] = acc[ns][r];
        }
    }
}

// ---------------- out-proj MFMA, pass-templated epilogue:
// PASS 0: write u_bf only; PASS 1: fuse xmid blend -> hc_bf directly
template<int PASS>
__global__ __launch_bounds__(256) void k_proj_out_t(const __hip_bfloat16* __restrict__ ynbf,
    const __hip_bfloat16* __restrict__ wbf, const float* __restrict__ xmid,
    const float* __restrict__ gate1,
    __hip_bfloat16* __restrict__ ubf, __hip_bfloat16* __restrict__ hcbf)
{
    __shared__ __align__(16) short Abuf[64][136];
    __shared__ __align__(16) short Wbuf[128][136];
    const int tid = threadIdx.x;
    const int m0 = blockIdx.x*64;
    const int lane = tid & 63, wv = tid >> 6, fr = lane & 15, q = lane >> 4;
    f32x4 acc[8];
    #pragma unroll
    for (int i = 0; i < 8; ++i) acc[i] = (f32x4){0.f,0.f,0.f,0.f};
    for (int kb = 0; kb < 2; ++kb) {
        if (kb) __syncthreads();
        for (int i = tid; i < 64*16; i += 256) {
            int r = i >> 4, s = i & 15;
            *(uint4*)&Abuf[r][s*8] = *(const uint4*)&ynbf[(size_t)(m0+r)*DIN + kb*128 + s*8];
        }
        for (int i = tid; i < 128*16; i += 256) {
            int r = i >> 4, s = i & 15;
            *(uint4*)&Wbuf[r][s*8] = *(const uint4*)&wbf[(size_t)r*DIN + kb*128 + s*8];
        }
        __syncthreads();
        #pragma unroll
        for (int kt = 0; kt < 4; ++kt) {
            short8 af = *reinterpret_cast<const short8*>(&Abuf[wv*16 + fr][kt*32 + q*8]);
            #pragma unroll
            for (int ns = 0; ns < 8; ++ns) {
                short8 bf = *reinterpret_cast<const short8*>(&Wbuf[ns*16 + fr][kt*32 + q*8]);
                acc[ns] = __builtin_amdgcn_mfma_f32_16x16x32_bf16(af, bf, acc[ns], 0, 0, 0);
            }
        }
    }
    float ca = 0.f, cb = 0.f;
    if (PASS == 1) {
        float al = 1.f / (1.f + expf(-gate1[0]));
        ca = 1.f + al; cb = 1.f - al;
    }
    #pragma unroll
    for (int ns = 0; ns < 8; ++ns)
        #pragma unroll
        for (int r = 0; r < 4; ++r) {
            int m = m0 + wv*16 + q*4 + r, n = ns*16 + fr;
            float v = acc[ns][r];
            if (PASS == 0) {
                ubf[(size_t)m*DM + n] = __float2bfloat16(v);
            } else {
                float xm = xmid[(size_t)m*DM + n];
                hcbf[(size_t)m*DM + n] = __float2bfloat16(ca*xm + cb*v);
            }
        }
}

// ---------------- up-proj MFMA + bias + residual + transpose store
__global__ __launch_bounds__(256) void k_up_mfma(const __hip_bfloat16* __restrict__ hc,
    const __hip_bfloat16* __restrict__ wbf, const float* __restrict__ b_up,
    const float* __restrict__ x, float* __restrict__ out)
{
    __shared__ __align__(16) short Abuf[64][136];
    __shared__ __align__(16) short Wbuf[128][136];
    const int tid = threadIdx.x;
    const int m0 = blockIdx.x*64;
    const int n0 = blockIdx.y*128;
    for (int i = tid; i < 64*16; i += 256) {
        int r = i >> 4, s = i & 15;
        *(uint4*)&Abuf[r][s*8] = *(const uint4*)&hc[(size_t)(m0+r)*DM + s*8];
    }
    for (int i = tid; i < 128*16; i += 256) {
        int r = i >> 4, s = i & 15;
        *(uint4*)&Wbuf[r][s*8] = *(const uint4*)&wbf[(size_t)(n0+r)*DM + s*8];
    }
    __syncthreads();
    const int lane = tid & 63, wv = tid >> 6, fr = lane & 15, q = lane >> 4;
    f32x4 acc[8];
    #pragma unroll
    for (int i = 0; i < 8; ++i) acc[i] = (f32x4){0.f,0.f,0.f,0.f};
    #pragma unroll
    for (int kt = 0; kt < 4; ++kt) {
        short8 af = *reinterpret_cast<const short8*>(&Abuf[wv*16 + fr][kt*32 + q*8]);
        #pragma unroll
        for (int ns = 0; ns < 8; ++ns) {
            short8 bf = *reinterpret_cast<const short8*>(&Wbuf[ns*16 + fr][kt*32 + q*8]);
            acc[ns] = __builtin_amdgcn_mfma_f32_16x16x32_bf16(af, bf, acc[ns], 0, 0, 0);
        }
    }
    #pragma unroll
    for (int r = 0; r < 4; ++r) {
        int m = m0 + wv*16 + q*4 + r;
        int b = m >> 11, l = m & 2047;
        size_t rowbase = (size_t)(l*NB + b)*HID + n0;
        #pragma unroll
        for (int ns = 0; ns < 8; ++ns) {
            int n = ns*16 + fr;
            out[rowbase + n] = acc[ns][r] + b_up[n0 + n] + x[rowbase + n];
        }
    }
}

// ---------------- K3: causal depthwise conv7 + bias + silu, one row per block.
// Threads 288..295 compute dt/dA and store transposed [dir][h][b][scan_pos].
__global__ __launch_bounds__(320) void k_conv(const float* __restrict__ zx,
    const float* __restrict__ cw, const float* __restrict__ cb,
    const float* __restrict__ dt_bias, const float* __restrict__ A_log,
    float* __restrict__ xBC, float* __restrict__ dtbuf, float* __restrict__ dAbuf)
{
    const int m = blockIdx.x;
    const int l = m & (SEQL-1), b = m >> 11;
    const int c = threadIdx.x;
    if (c < CONV_DIM) {
        float acc = cb[c];
        #pragma unroll
        for (int k = 0; k < 7; ++k) {
            int l2 = l - 6 + k;
            if (l2 >= 0)
                acc = fmaf(zx[(size_t)(b*SEQL + l2)*DPROJ + DIN + c], cw[c*7 + k], acc);
        }
        xBC[(size_t)m*CONV_DIM + c] = siluf(acc);
    } else if (c < CONV_DIM + 2*NH) {
        int j = c - CONV_DIM;
        int dir = j >> 2, hh = j & 3;
        float dtraw = zx[(size_t)(b*SEQL + l)*DPROJ + 544 + j] + dt_bias[hh];
        float dt = dtraw > 20.f ? dtraw : log1pf(expf(dtraw));
        float dA = expf(dt * (-expf(A_log[hh])));
        int pos = dir ? (SEQL-1 - l) : l;
        size_t o = (size_t)((dir*NH + hh)*NB + b)*SEQL + pos;
        dtbuf[o] = dt; dAbuf[o] = dA;
    }
}

// ---------------- K4a: chunk-local scan states (256 threads, 4 waves)
__global__ __launch_bounds__(256) void k_scan_state(const float* __restrict__ xBC,
    const float* __restrict__ dtbuf, const float* __restrict__ dAbuf,
    float* __restrict__ Sbuf, float* __restrict__ Pbuf)
{
    const int bid = blockIdx.x;
    const int c   = bid & (NCHUNK-1);
    const int h   = (bid >> 5) & (NH-1);
    const int b   = (bid >> 7) & 3;
    const int dir = bid >> 9;
    const int tid = threadIdx.x;
    __shared__ float dA_s[TCH], dt_s[TCH];
    __shared__ __align__(16) float Xs[TCH][HD];
    __shared__ __align__(16) float Bs[TCH][DST];
    const size_t tb = (size_t)((dir*NH + h)*NB + b)*SEQL + c*TCH;
    if (tid < TCH) {
        dt_s[tid] = dtbuf[tb + tid];
        dA_s[tid] = dAbuf[tb + tid];
    }
    __syncthreads();
    #pragma unroll
    for (int t = 0; t < 4; ++t) {
        int idx = t*256 + tid;
        int k2 = idx >> 4, p4 = (idx & 15)*4;
        int l2 = dir ? (SEQL-1 - (c*TCH + k2)) : (c*TCH + k2);
        float4 v = *(const float4*)&xBC[(size_t)(b*SEQL + l2)*CONV_DIM + h*HD + p4];
        float sc = dt_s[k2];
        v.x *= sc; v.y *= sc; v.z *= sc; v.w *= sc;
        *(float4*)&Xs[k2][p4] = v;
    }
    {
        int k2 = tid >> 2, n4 = (tid & 3)*4;
        int l2 = dir ? (SEQL-1 - (c*TCH + k2)) : (c*TCH + k2);
        *(float4*)&Bs[k2][n4] = *(const float4*)&xBC[(size_t)(b*SEQL + l2)*CONV_DIM + DIN + n4];
    }
    __syncthreads();
    const int lane = tid & 63, w = tid >> 6;
    const int p = w*16 + (lane >> 2), ng = lane & 3;
    float s[4] = {0.f, 0.f, 0.f, 0.f};
    for (int k2 = 0; k2 < TCH; ++k2) {
        float dAv = dA_s[k2];
        float xa  = Xs[k2][p];
        float4 bv = *(const float4*)&Bs[k2][ng*4];
        s[0] = fmaf(dAv, s[0], xa*bv.x);
        s[1] = fmaf(dAv, s[1], xa*bv.y);
        s[2] = fmaf(dAv, s[2], xa*bv.z);
        s[3] = fmaf(dAv, s[3], xa*bv.w);
    }
    const size_t sb = (size_t)bid * 1024;
    float4 sv = {s[0], s[1], s[2], s[3]};
    *(float4*)&Sbuf[sb + (size_t)(p*16 + ng*4)] = sv;
    if (w == 0) {
        float pv = dA_s[lane];
        #pragma unroll
        for (int o = 32; o > 0; o >>= 1) pv *= __shfl_xor(pv, o, 64);
        if (lane == 0) Pbuf[bid] = pv;
    }
}

// ---------------- K4c: replay with in-block register prefix (combine folded in)
__global__ __launch_bounds__(256) void k_scan_out2(const float* __restrict__ xBC,
    const float* __restrict__ dtbuf, const float* __restrict__ dAbuf,
    const float* __restrict__ Sbuf, const float* __restrict__ Pbuf,
    float* __restrict__ yfw, float* __restrict__ ybw)
{
    const int bid = blockIdx.x;
    const int cs  = bid & (NCHUNK-1);
    const int h   = (bid >> 5) & (NH-1);
    const int b   = (bid >> 7) & 3;
    const int dir = bid >> 9;
    const int tid = threadIdx.x;
    __shared__ float dA_s[TCH], dt_s[TCH];
    __shared__ __align__(16) float Xs[TCH][HD];
    __shared__ __align__(16) float Bs[TCH][DST];
    __shared__ __align__(16) float Cs[TCH][DST];
    const size_t tb = (size_t)((dir*NH + h)*NB + b)*SEQL + cs*TCH;
    if (tid < TCH) { dt_s[tid] = dtbuf[tb + tid]; dA_s[tid] = dAbuf[tb + tid]; }
    __syncthreads();
    #pragma unroll
    for (int t = 0; t < 4; ++t) {
        int idx = t*256 + tid;
        int k2 = idx >> 4, p4 = (idx & 15)*4;
        int l2 = dir ? (SEQL-1 - (cs*TCH + k2)) : (cs*TCH + k2);
        float4 v = *(const float4*)&xBC[(size_t)(b*SEQL + l2)*CONV_DIM + h*HD + p4];
        float sc = dt_s[k2];
        v.x *= sc; v.y *= sc; v.z *= sc; v.w *= sc;
        *(float4*)&Xs[k2][p4] = v;
    }
    {
        int k2 = tid >> 2, n4 = (tid & 3)*4;
        int l2 = dir ? (SEQL-1 - (cs*TCH + k2)) : (cs*TCH + k2);
        *(float4*)&Bs[k2][n4] = *(const float4*)&xBC[(size_t)(b*SEQL + l2)*CONV_DIM + DIN + n4];
        *(float4*)&Cs[k2][n4] = *(const float4*)&xBC[(size_t)(b*SEQL + l2)*CONV_DIM + DIN + DST + n4];
    }
    // H-init: register prefix over earlier chunks of this chain (proven in R4)
    const int lane = tid & 63, w = tid >> 6;
    const int p = w*16 + (lane >> 2), ng = lane & 3;
    const float* Sg = Sbuf + (size_t)(bid - cs)*1024 + (p*16 + ng*4);
    const float* Pg = Pbuf + (bid - cs);
    float4 carry = {0.f,0.f,0.f,0.f};
    for (int jb = 0; jb < cs; jb += 8) {
        float4 sv[8]; float pw[8];
        #pragma unroll
        for (int k = 0; k < 8; ++k) {
            int j = jb + k;
            if (j < cs) { sv[k] = *(const float4*)(Sg + (size_t)j*1024); pw[k] = Pg[j]; }
            else        { sv[k] = (float4){0.f,0.f,0.f,0.f}; pw[k] = 1.f; }
        }
        #pragma unroll
        for (int k = 0; k < 8; ++k) {
            carry.x = fmaf(pw[k], carry.x, sv[k].x);
            carry.y = fmaf(pw[k], carry.y, sv[k].y);
            carry.z = fmaf(pw[k], carry.z, sv[k].z);
            carry.w = fmaf(pw[k], carry.w, sv[k].w);
        }
    }
    __syncthreads();
    float s0 = carry.x, s1 = carry.y, s2 = carry.z, s3 = carry.w;
    float* yout = dir ? ybw : yfw;
    for (int k2 = 0; k2 < TCH; ++k2) {
        float dAv = dA_s[k2];
        float xa  = Xs[k2][p];
        float4 bv = *(const float4*)&Bs[k2][ng*4];
        float4 cv = *(const float4*)&Cs[k2][ng*4];
        s0 = fmaf(dAv, s0, xa*bv.x);
        s1 = fmaf(dAv, s1, xa*bv.y);
        s2 = fmaf(dAv, s2, xa*bv.z);
        s3 = fmaf(dAv, s3, xa*bv.w);
        float yp = s0*cv.x + s1*cv.y + s2*cv.z + s3*cv.w;
        yp += __shfl_xor(yp, 1, 64);
        yp += __shfl_xor(yp, 2, 64);
        if (ng == 0) {
            int l2 = dir ? (SEQL-1 - (cs*TCH + k2)) : (cs*TCH + k2);
            yout[(size_t)(b*SEQL + l2)*DIN + h*HD + p] = yp;
        }
    }
}

// ---------------- K5: shift-combine + D-skip + gate + RMSNorm -> yn (bf16)
__global__ __launch_bounds__(256) void k_epi(const float* __restrict__ zx,
    const float* __restrict__ xBC, const float* __restrict__ yfw,
    const float* __restrict__ ybw, const float* __restrict__ fcD_w,
    const float* __restrict__ Dv, const float* __restrict__ norm_w,
    __hip_bfloat16* __restrict__ ynbf)
{
    const int m = blockIdx.x;
    const int l = m & (SEQL-1);
    const int d = threadIdx.x;
    const int lane = d & 63, wave = d >> 6;
    __shared__ float red[4][4];
    __shared__ float redq[4];
    float xs = xBC[(size_t)m*CONV_DIM + d];
    float yv = 0.f;
    if (l > 0)       yv += yfw[(size_t)(m-1)*DIN + d];
    if (l < SEQL-1)  yv += ybw[(size_t)(m+1)*DIN + d];
    float p0 = wave_sum(xs * fcD_w[0*DIN + d]);
    float p1 = wave_sum(xs * fcD_w[1*DIN + d]);
    float p2 = wave_sum(xs * fcD_w[2*DIN + d]);
    float p3 = wave_sum(xs * fcD_w[3*DIN + d]);
    if (lane == 0) { red[wave][0]=p0; red[wave][1]=p1; red[wave][2]=p2; red[wave][3]=p3; }
    __syncthreads();
    const int h = d >> 6;
    float scal = red[0][h] + red[1][h] + red[2][h] + red[3][h] + Dv[h];
    yv = fmaf(xs, scal, yv);
    float z  = zx[(size_t)m*DPROJ + d];
    float yz = yv * siluf(z);
    float q = wave_sum(yz*yz);
    if (lane == 0) redq[wave] = q;
    __syncthreads();
    float ms = (redq[0] + redq[1] + redq[2] + redq[3]) * (1.f/DIN);
    float r = rsqrtf(ms + 1e-5f);
    ynbf[(size_t)m*DIN + d] = __float2bfloat16(yz * r * norm_w[d]);
}

extern "C" void kernel_launch(void* const* d_in, const int* in_sizes, int n_in,
                              void* d_out, int out_size, void* d_ws, size_t ws_size,
                              hipStream_t stream)
{
    const float* x       = (const float*)d_in[0];
    const float* w_down  = (const float*)d_in[1];
    const float* b_down  = (const float*)d_in[2];
    const float* w_up    = (const float*)d_in[3];
    const float* b_up    = (const float*)d_in[4];
    const float* gate1   = (const float*)d_in[5];
    const float* in_w    = (const float*)d_in[6];
    const float* conv_w  = (const float*)d_in[7];
    const float* conv_b  = (const float*)d_in[8];
    const float* dt_bias = (const float*)d_in[9];
    const float* A_log   = (const float*)d_in[10];
    const float* Dv      = (const float*)d_in[11];
    const float* fcD_w   = (const float*)d_in[12];
    const float* norm_w  = (const float*)d_in[13];
    const float* out_w   = (const float*)d_in[14];
    float* out = (float*)d_out;
    float* ws  = (float*)d_ws;

    size_t off = 0;
    float* xmid = ws + off; off += (size_t)MROWS*DM;
    float* zx   = ws + off; off += (size_t)MROWS*DPROJ;
    float* xBC  = ws + off; off += (size_t)MROWS*CONV_DIM;
    float* yfw  = ws + off; off += (size_t)MROWS*DIN;
    float* ybw  = ws + off; off += (size_t)MROWS*DIN;
    float* Sbuf = ws + off; off += (size_t)1024*1024;
    float* Pbuf = ws + off; off += 1024;
    float* dtbuf= ws + off; off += (size_t)2*NH*NB*SEQL;
    float* dAbuf= ws + off; off += (size_t)2*NH*NB*SEQL;
    __hip_bfloat16* bfb = (__hip_bfloat16*)(ws + off);
    size_t bo = 0;
    __hip_bfloat16* wd_bf = bfb + bo; bo += 524288;
    __hip_bfloat16* wu_bf = bfb + bo; bo += 524288;
    __hip_bfloat16* wi_bf = bfb + bo; bo += 71680;
    __hip_bfloat16* wo_bf = bfb + bo; bo += 32768;
    __hip_bfloat16* u_bf  = bfb + bo; bo += (size_t)MROWS*DM;
    __hip_bfloat16* yn_bf = bfb + bo; bo += (size_t)MROWS*DIN;
    __hip_bfloat16* hc_bf = bfb + bo; bo += (size_t)MROWS*DM;
    float* partial = zx;   // alias: 4*MROWS*DM = 4.19M floats <= MROWS*552 = 4.52M

    k_prep_w<<<4504, 256, 0, stream>>>(w_down, w_up, in_w, out_w, wd_bf, wu_bf, wi_bf, wo_bf);

    dim3 gdown(MROWS/64, KSPLIT);
    k_down_mfma<<<gdown, 256, 0, stream>>>(x, wd_bf, partial);
    k_down_fix<<<MROWS*DM/1024, 256, 0, stream>>>(partial, b_down, xmid, u_bf);

    for (int pass = 0; pass < 2; ++pass) {
        dim3 gin(MROWS/64, 7);
        k_proj_in<<<gin, 256, 0, stream>>>(u_bf, wi_bf, zx);
        k_conv<<<MROWS, 320, 0, stream>>>(zx, conv_w, conv_b, dt_bias, A_log, xBC, dtbuf, dAbuf);
        k_scan_state<<<1024, 256, 0, stream>>>(xBC, dtbuf, dAbuf, Sbuf, Pbuf);
        k_scan_out2<<<1024, 256, 0, stream>>>(xBC, dtbuf, dAbuf, Sbuf, Pbuf, yfw, ybw);
        k_epi<<<MROWS, 256, 0, stream>>>(zx, xBC, yfw, ybw, fcD_w, Dv, norm_w, yn_bf);
        if (pass == 0)
            k_proj_out_t<0><<<MROWS/64, 256, 0, stream>>>(yn_bf, wo_bf, xmid, gate1, u_bf, hc_bf);
        else
            k_proj_out_t<1><<<MROWS/64, 256, 0, stream>>>(yn_bf, wo_bf, xmid, gate1, u_bf, hc_bf);
    }

    dim3 gup(MROWS/64, HID/128);
    k_up_mfma<<<gup, 256, 0, stream>>>(hc_bf, wu_bf, b_up, x, out);
}